// Round 5
// baseline (243.404 us; speedup 1.0000x reference)
//
#include <hip/hip_runtime.h>
#include <hip/hip_bf16.h>

typedef __bf16 bf16x8 __attribute__((ext_vector_type(8)));
typedef float f32x4 __attribute__((ext_vector_type(4)));
typedef __attribute__((address_space(3))) void lds_void_t;
typedef __attribute__((address_space(1))) void gbl_void_t;

#define LRELU(x) ((x) >= 0.f ? (x) : 0.2f * (x))

__device__ __forceinline__ void gload16(void* lds_uniform, const void* gsrc) {
    __builtin_amdgcn_global_load_lds((const gbl_void_t*)gsrc, (lds_void_t*)lds_uniform,
                                     16, 0, 0);
}

__device__ __forceinline__ unsigned short f2u(float f) {
    __hip_bfloat16 h = __float2bfloat16(f);
    return reinterpret_cast<unsigned short&>(h);
}

// ---------------- f32 -> bf16 convert (vector4) ----------------------------
__global__ void cvt_f32_bf16(const float* __restrict__ in,
                             __hip_bfloat16* __restrict__ out, int n4) {
    int stride = gridDim.x * blockDim.x;
    for (int i = blockIdx.x * blockDim.x + threadIdx.x; i < n4; i += stride) {
        float4 v = reinterpret_cast<const float4*>(in)[i];
        ushort4 o;
        o.x = f2u(v.x); o.y = f2u(v.y); o.z = f2u(v.z); o.w = f2u(v.w);
        reinterpret_cast<ushort4*>(out)[i] = o;
    }
}

// ---------------- 256x256 tile GEMM, BK=32, triple-buffer, 2-phase pairs ---
// 8 waves (2M x 4N), per-wave output 128x64 (8x4 fragments 16x16x32 bf16).
// LDS: 3 buffers x (A 8192 + B 8192 elements) = 96 KB.
// Per K-tile t (buf t%3), template-faithful phase choreography:
//  P1: ds_read af[0-3],bfr[0-3] | STAGE_A(t+2) | bar | lgkm(0) | 16 MFMA | bar
//  P2: ds_read af[4-7]          | STAGE_B(t+2) | vmcnt(4) | bar | lgkm(0)
//      | 16 MFMA | bar
// Ledger: RAW  - tile t's buf verified at t-1's P2 vmcnt(4)+barrier (keeps only
//               the 4 newest loads = tile t+1 stages; tile t's landed).
//         WAR  - STAGE(t+2) writes buf (t-1)%3; its last reads drained at
//               t-1 P2 lgkmcnt(0), ordered block-wide by t-1's end barrier.
//         WAW  - prior DMA to that buf (issued t-3) verified landed at t-2.
// MODE 1: out = bf16( lrelu(bn(A@B^T)) + xq[b][col] )   (features)
// MODE 2: out = bf16( lrelu(bn(A@B^T)) )                (s2)
template <int N, int K, int MODE>
__global__ __launch_bounds__(512, 2)
void gemm256(const __hip_bfloat16* __restrict__ A,
             const __hip_bfloat16* __restrict__ Bw,
             const float* __restrict__ xq,
             __hip_bfloat16* __restrict__ out,
             const float* __restrict__ Gg, const float* __restrict__ Gb,
             const float* __restrict__ Gm, const float* __restrict__ Gv) {
    __shared__ __hip_bfloat16 sm[3 * 16384];

    // XCD-aware block swizzle (nwg % 8 == 0 guaranteed by launch config)
    const int nwg = gridDim.x;
    const int cpx = nwg >> 3;
    const int bid = blockIdx.x;
    const int orig = (bid & 7) * cpx + (bid >> 3);
    constexpr int NCB = N / 256;
    const int rowblk = orig / NCB;
    const int colblk = orig % NCB;
    const int row0 = rowblk * 256, col0 = colblk * 256;

    const int tid = threadIdx.x;
    const int lane = tid & 63;
    const int wv = tid >> 6;          // 0..7
    const int wm = wv >> 2, wn = wv & 3;
    const int lr = lane & 15, kg = lane >> 4;

    // ---- staging source addresses (pre-swizzled global chunks) ----
    const int srow = tid >> 2;        // dest row (mod 128)
    const int sc = tid & 3;           // dest 16B-chunk position
    const int kch = ((sc ^ ((srow >> 1) & 3)) << 3);  // source k-chunk (elements)
    const __hip_bfloat16* As0 = A + (size_t)(row0 + srow) * K + kch;
    const __hip_bfloat16* As1 = A + (size_t)(row0 + 128 + srow) * K + kch;
    const __hip_bfloat16* Bs0 = Bw + (size_t)(col0 + srow) * K + kch;
    const __hip_bfloat16* Bs1 = Bw + (size_t)(col0 + 128 + srow) * K + kch;

    auto STAGE_A = [&](int b, int k0) {
        __hip_bfloat16* la = sm + b * 16384 + wv * 512;  // per-wave uniform base
        gload16(la,        As0 + k0);
        gload16(la + 4096, As1 + k0);
    };
    auto STAGE_B = [&](int b, int k0) {
        __hip_bfloat16* lb = sm + b * 16384 + 8192 + wv * 512;
        gload16(lb,        Bs0 + k0);
        gload16(lb + 4096, Bs1 + k0);
    };

    // ---- ds_read fragment offsets (swizzled chunk) ----
    const int f = (lr >> 1) & 3;
    const int koff = ((kg ^ f) << 3);
    const int aoff = (wm * 128 + lr) * 32 + koff;          // A: elements
    const int boff = 8192 + (wn * 64 + lr) * 32 + koff;    // B: elements

    f32x4 acc[8][4];
#pragma unroll
    for (int i = 0; i < 8; ++i)
#pragma unroll
        for (int j = 0; j < 4; ++j) acc[i][j] = (f32x4){0.f, 0.f, 0.f, 0.f};

    constexpr int nt = K / 32;
    STAGE_A(0, 0);  STAGE_B(0, 0);
    STAGE_A(1, 32); STAGE_B(1, 32);
    asm volatile("s_waitcnt vmcnt(4)" ::: "memory");   // tile 0 landed
    __builtin_amdgcn_s_barrier();

    for (int t = 0; t < nt; ++t) {
        const __hip_bfloat16* base = sm + (t % 3) * 16384;
        bf16x8 af[8], bfr[4];

        // ================= phase 1 =================
#pragma unroll
        for (int i = 0; i < 4; ++i)
            af[i] = *reinterpret_cast<const bf16x8*>(base + aoff + i * 512);
#pragma unroll
        for (int j = 0; j < 4; ++j)
            bfr[j] = *reinterpret_cast<const bf16x8*>(base + boff + j * 512);
        if (t + 2 < nt) STAGE_A((t + 2) % 3, (t + 2) * 32);

        __builtin_amdgcn_s_barrier();
        asm volatile("s_waitcnt lgkmcnt(0)" ::: "memory");
        __builtin_amdgcn_sched_barrier(0);
        __builtin_amdgcn_s_setprio(1);
#pragma unroll
        for (int i = 0; i < 4; ++i)
#pragma unroll
            for (int j = 0; j < 4; ++j)
                acc[i][j] = __builtin_amdgcn_mfma_f32_16x16x32_bf16(af[i], bfr[j], acc[i][j], 0, 0, 0);
        __builtin_amdgcn_s_setprio(0);
        __builtin_amdgcn_sched_barrier(0);
        __builtin_amdgcn_s_barrier();

        // ================= phase 2 =================
#pragma unroll
        for (int i = 4; i < 8; ++i)
            af[i] = *reinterpret_cast<const bf16x8*>(base + aoff + i * 512);
        if (t + 2 < nt) {
            STAGE_B((t + 2) % 3, (t + 2) * 32);
            asm volatile("s_waitcnt vmcnt(4)" ::: "memory");  // tile t+1 landed
        } else if (t + 1 < nt) {
            asm volatile("s_waitcnt vmcnt(0)" ::: "memory");
        }
        __builtin_amdgcn_s_barrier();
        asm volatile("s_waitcnt lgkmcnt(0)" ::: "memory");
        __builtin_amdgcn_sched_barrier(0);
        __builtin_amdgcn_s_setprio(1);
#pragma unroll
        for (int i = 4; i < 8; ++i)
#pragma unroll
            for (int j = 0; j < 4; ++j)
                acc[i][j] = __builtin_amdgcn_mfma_f32_16x16x32_bf16(af[i], bfr[j], acc[i][j], 0, 0, 0);
        __builtin_amdgcn_s_setprio(0);
        __builtin_amdgcn_sched_barrier(0);
        __builtin_amdgcn_s_barrier();
    }

    // ---- epilogue: BN + LeakyReLU (+ xq for MODE 1) ----
    const int bq = row0 >> 11;  // batch index (tile rows within one batch)
#pragma unroll
    for (int j = 0; j < 4; ++j) {
        const int c = col0 + wn * 64 + j * 16 + lr;
        const float scl = Gg[c] * rsqrtf(Gv[c] + 1e-5f);
        const float tcn = Gb[c] - Gm[c] * scl;
        float xqv = 0.f;
        if constexpr (MODE == 1) xqv = xq[bq * 2048 + c];
#pragma unroll
        for (int i = 0; i < 8; ++i) {
            const int r = row0 + wm * 128 + i * 16 + kg * 4;
#pragma unroll
            for (int rI = 0; rI < 4; ++rI) {
                float val = acc[i][j][rI] * scl + tcn;
                val = LRELU(val) + xqv;
                out[(size_t)(r + rI) * N + c] = __float2bfloat16(val);
            }
        }
    }
}

// ---------------- GEMM3 (M x 64, K=512) fused with layer-4 + bn4 ----------
__global__ __launch_bounds__(256)
void gemm3_l4(const __hip_bfloat16* __restrict__ A,    // s2b [M,512]
              const __hip_bfloat16* __restrict__ W3b,  // [64,512]
              const float* __restrict__ W4,            // [64]
              const float* __restrict__ g3, const float* __restrict__ b3,
              const float* __restrict__ m3, const float* __restrict__ v3,
              const float* __restrict__ g4, const float* __restrict__ b4,
              const float* __restrict__ m4, const float* __restrict__ v4,
              float* __restrict__ logits) {
    const int lane = threadIdx.x & 63;
    const int wv = threadIdx.x >> 6;
    const int row0 = blockIdx.x * 128 + wv * 32;
    const int lr = lane & 15, kg = lane >> 4;

    f32x4 acc[2][4];
#pragma unroll
    for (int i = 0; i < 2; ++i)
#pragma unroll
        for (int j = 0; j < 4; ++j) acc[i][j] = (f32x4){0.f, 0.f, 0.f, 0.f};

    for (int k = 0; k < 512; k += 32) {
        const int kk = k + kg * 8;
        bf16x8 a[2], b[4];
#pragma unroll
        for (int i = 0; i < 2; ++i)
            a[i] = *reinterpret_cast<const bf16x8*>(A + (size_t)(row0 + i * 16 + lr) * 512 + kk);
#pragma unroll
        for (int j = 0; j < 4; ++j)
            b[j] = *reinterpret_cast<const bf16x8*>(W3b + (size_t)(j * 16 + lr) * 512 + kk);
#pragma unroll
        for (int i = 0; i < 2; ++i)
#pragma unroll
            for (int j = 0; j < 4; ++j)
                acc[i][j] = __builtin_amdgcn_mfma_f32_16x16x32_bf16(a[i], b[j], acc[i][j], 0, 0, 0);
    }

    const float sc4 = g4[0] * rsqrtf(v4[0] + 1e-5f);
    const float tc4 = b4[0] - m4[0] * sc4;
#pragma unroll
    for (int i = 0; i < 2; ++i) {
        float t[4] = {0.f, 0.f, 0.f, 0.f};
#pragma unroll
        for (int j = 0; j < 4; ++j) {
            const int c = j * 16 + lr;
            const float sc = g3[c] * rsqrtf(v3[c] + 1e-5f);
            const float tc = b3[c] - m3[c] * sc;
            const float w4c = W4[c];
#pragma unroll
            for (int rI = 0; rI < 4; ++rI) {
                float v = acc[i][j][rI] * sc + tc;
                t[rI] += LRELU(v) * w4c;
            }
        }
#pragma unroll
        for (int m = 1; m < 16; m <<= 1)
#pragma unroll
            for (int rI = 0; rI < 4; ++rI) t[rI] += __shfl_xor(t[rI], m, 64);
        if (lr == 0) {
#pragma unroll
            for (int rI = 0; rI < 4; ++rI) {
                float lg = t[rI] * sc4 + tc4;
                logits[row0 + i * 16 + kg * 4 + rI] = LRELU(lg);
            }
        }
    }
}

// ---------------- softmax over N=2048 per batch ----------------------------
__global__ void softmax2048(const float* __restrict__ logits, float* __restrict__ scores) {
    __shared__ float sh[2048];
    __shared__ float red[256];
    const int b = blockIdx.x, tid = threadIdx.x;
    float lmax = -1e30f;
#pragma unroll
    for (int it = 0; it < 8; ++it) {
        const int n = tid + it * 256;
        float v = logits[b * 2048 + n];
        sh[n] = v;
        lmax = fmaxf(lmax, v);
    }
    red[tid] = lmax;
    __syncthreads();
    for (int s = 128; s > 0; s >>= 1) {
        if (tid < s) red[tid] = fmaxf(red[tid], red[tid + s]);
        __syncthreads();
    }
    const float gmax = red[0];
    __syncthreads();
    float lsum = 0.f;
#pragma unroll
    for (int it = 0; it < 8; ++it) {
        const int n = tid + it * 256;
        float e = expf(sh[n] - gmax);
        sh[n] = e;
        lsum += e;
    }
    red[tid] = lsum;
    __syncthreads();
    for (int s = 128; s > 0; s >>= 1) {
        if (tid < s) red[tid] += red[tid + s];
        __syncthreads();
    }
    const float inv = 1.f / red[0];
#pragma unroll
    for (int it = 0; it < 8; ++it) {
        const int n = tid + it * 256;
        scores[b * 2048 + n] = sh[n] * inv;
    }
}

// ---------------- pooling over features, then subtract xq ------------------
// out[b,e] = sum_n features[b,n,e]*scores[b,n] - xq[b,e]   (sum scores = 1)
__global__ void pool_partial(const __hip_bfloat16* __restrict__ feats,
                             const float* __restrict__ scores,
                             float* __restrict__ partial) {
    const int b = blockIdx.y, nc = blockIdx.x;  // 32 chunks of 64 rows
    const int e0 = threadIdx.x * 8;
    float acc[8] = {0, 0, 0, 0, 0, 0, 0, 0};
    const size_t base = ((size_t)b * 2048 + nc * 64) * 2048;
    for (int i = 0; i < 64; ++i) {
        const float sc = scores[b * 2048 + nc * 64 + i];
        bf16x8 v = *reinterpret_cast<const bf16x8*>(feats + base + (size_t)i * 2048 + e0);
#pragma unroll
        for (int j = 0; j < 8; ++j) acc[j] += sc * (float)v[j];
    }
    float* p = partial + ((size_t)(b * 32 + nc)) * 2048 + e0;
#pragma unroll
    for (int j = 0; j < 8; ++j) p[j] = acc[j];
}

__global__ void pool_reduce(const float* __restrict__ partial,
                            const float* __restrict__ xq,
                            float* __restrict__ out) {
    const int i = blockIdx.x * blockDim.x + threadIdx.x;  // 0..32767
    const int b = i >> 11, e = i & 2047;
    float s = 0.f;
#pragma unroll
    for (int nc = 0; nc < 32; ++nc) s += partial[((size_t)(b * 32 + nc)) * 2048 + e];
    out[i] = s - xq[i];
}

// ---------------------------------------------------------------------------
extern "C" void kernel_launch(void* const* d_in, const int* in_sizes, int n_in,
                              void* d_out, int out_size, void* d_ws, size_t ws_size,
                              hipStream_t stream) {
    const float* xq = (const float*)d_in[0];
    const float* xk = (const float*)d_in[1];
    const float* W1 = (const float*)d_in[2];
    const float* W2 = (const float*)d_in[3];
    const float* W3 = (const float*)d_in[4];
    const float* W4 = (const float*)d_in[5];
    const float* g1 = (const float*)d_in[6], *b1 = (const float*)d_in[7];
    const float* m1 = (const float*)d_in[8], *v1 = (const float*)d_in[9];
    const float* g2 = (const float*)d_in[10], *b2 = (const float*)d_in[11];
    const float* m2 = (const float*)d_in[12], *v2 = (const float*)d_in[13];
    const float* g3 = (const float*)d_in[14], *b3 = (const float*)d_in[15];
    const float* m3 = (const float*)d_in[16], *v3 = (const float*)d_in[17];
    const float* g4 = (const float*)d_in[18], *b4 = (const float*)d_in[19];
    const float* m4 = (const float*)d_in[20], *v4 = (const float*)d_in[21];

    const int M = 32768;  // B*N = 16*2048

    char* ws = (char*)d_ws;
    size_t off = 0;
    auto alloc = [&](size_t bytes) {
        void* p = ws + off;
        off += (bytes + 255) & ~(size_t)255;
        return p;
    };
    __hip_bfloat16* xkb   = (__hip_bfloat16*)alloc((size_t)M * 512 * 2);
    __hip_bfloat16* w1b   = (__hip_bfloat16*)alloc((size_t)2048 * 512 * 2);
    __hip_bfloat16* w2b   = (__hip_bfloat16*)alloc((size_t)512 * 2048 * 2);
    __hip_bfloat16* w3b   = (__hip_bfloat16*)alloc((size_t)64 * 512 * 2);
    __hip_bfloat16* featb = (__hip_bfloat16*)alloc((size_t)M * 2048 * 2);
    __hip_bfloat16* s2b   = (__hip_bfloat16*)alloc((size_t)M * 512 * 2);
    float* logits         = (float*)alloc((size_t)M * 4);
    float* scores         = (float*)alloc((size_t)16 * 2048 * 4);
    float* partial        = (float*)alloc((size_t)16 * 32 * 2048 * 4);

    // converts
    cvt_f32_bf16<<<4096, 256, 0, stream>>>(xk, xkb, M * 512 / 4);
    cvt_f32_bf16<<<1024, 256, 0, stream>>>(W1, w1b, 2048 * 512 / 4);
    cvt_f32_bf16<<<1024, 256, 0, stream>>>(W2, w2b, 512 * 2048 / 4);
    cvt_f32_bf16<<<32, 256, 0, stream>>>(W3, w3b, 64 * 512 / 4);

    // GEMM1: features = lrelu(bn1(xk @ W1^T)) + xq   [M,2048] bf16
    gemm256<2048, 512, 1><<<1024, 512, 0, stream>>>(
        xkb, w1b, xq, featb, g1, b1, m1, v1);

    // GEMM2: s2 = lrelu(bn2(features @ W2^T))        [M,512] bf16
    gemm256<512, 2048, 2><<<256, 512, 0, stream>>>(
        featb, w2b, nullptr, s2b, g2, b2, m2, v2);

    // GEMM3 + layer4: logits [M] f32
    gemm3_l4<<<256, 256, 0, stream>>>(s2b, w3b, W4,
                                      g3, b3, m3, v3, g4, b4, m4, v4, logits);

    // softmax over N per batch
    softmax2048<<<16, 256, 0, stream>>>(logits, scores);

    // pooling (+ subtract xq)
    pool_partial<<<dim3(32, 16), 256, 0, stream>>>(featb, scores, partial);
    pool_reduce<<<128, 256, 0, stream>>>(partial, xq, (float*)d_out);
}

// Round 6
// 221.490 us; speedup vs baseline: 1.0989x; 1.0989x over previous
//
#include <hip/hip_runtime.h>
#include <hip/hip_bf16.h>

typedef __bf16 bf16x8 __attribute__((ext_vector_type(8)));
typedef float f32x4 __attribute__((ext_vector_type(4)));
typedef __attribute__((address_space(3))) void lds_void_t;
typedef __attribute__((address_space(1))) void gbl_void_t;

#define LRELU(x) ((x) >= 0.f ? (x) : 0.2f * (x))

__device__ __forceinline__ void gload16(void* lds_uniform, const void* gsrc) {
    __builtin_amdgcn_global_load_lds((const gbl_void_t*)gsrc, (lds_void_t*)lds_uniform,
                                     16, 0, 0);
}

__device__ __forceinline__ unsigned short f2u(float f) {
    __hip_bfloat16 h = __float2bfloat16(f);
    return reinterpret_cast<unsigned short&>(h);
}

// ---------------- f32 -> bf16 convert (vector4) ----------------------------
__global__ void cvt_f32_bf16(const float* __restrict__ in,
                             __hip_bfloat16* __restrict__ out, int n4) {
    int stride = gridDim.x * blockDim.x;
    for (int i = blockIdx.x * blockDim.x + threadIdx.x; i < n4; i += stride) {
        float4 v = reinterpret_cast<const float4*>(in)[i];
        ushort4 o;
        o.x = f2u(v.x); o.y = f2u(v.y); o.z = f2u(v.z); o.w = f2u(v.w);
        reinterpret_cast<ushort4*>(out)[i] = o;
    }
}

// ---------------- 256x256 tile GEMM, BK=32, triple-buffer ------------------
// 8 waves (2M x 4N), per-wave output 128x64 (8x4 fragments 16x16x32 bf16).
// LDS: 3 buffers x (A 8192 + B 8192 elements) = 96 KB.
// Per K-tile: ONE counted vmcnt(4) + ONE barrier; body is a free-scheduling
// region: {STAGE(t+2) 4x gload_lds | 12x ds_read_b128 | 32x MFMA} with NO
// interior fences -- the compiler emits fine-grained lgkmcnt and interleaves
// reads under MFMAs (m97/m141 lesson: order-pinning regresses).
// Ledger: RAW - at top of t, outstanding <= {t's 4, t+1's 4}; vmcnt(4) drains
//               to 4 => tile t's loads landed (wave-uniform issue order);
//               barrier => all waves' slices landed.
//         WAR - STAGE(t+2) writes buf (t+2)%3, last read at t-1 (reads
//               consumed by MFMA deps before t-1's end == t's top barrier).
//         WAW - prior DMA to that buf issued at t-3, verified landed at t-1.
// MODE 1: out = bf16( lrelu(bn(A@B^T)) + xq[b][col] )   (features)
// MODE 2: out = bf16( lrelu(bn(A@B^T)) )                (s2)
template <int N, int K, int MODE>
__global__ __launch_bounds__(512, 2)
void gemm256(const __hip_bfloat16* __restrict__ A,
             const __hip_bfloat16* __restrict__ Bw,
             const float* __restrict__ xq,
             __hip_bfloat16* __restrict__ out,
             const float* __restrict__ Gg, const float* __restrict__ Gb,
             const float* __restrict__ Gm, const float* __restrict__ Gv) {
    __shared__ __hip_bfloat16 sm[3 * 16384];

    // XCD-aware block swizzle (nwg % 8 == 0 guaranteed by launch config)
    const int nwg = gridDim.x;
    const int cpx = nwg >> 3;
    const int bid = blockIdx.x;
    const int orig = (bid & 7) * cpx + (bid >> 3);
    constexpr int NCB = N / 256;
    const int rowblk = orig / NCB;
    const int colblk = orig % NCB;
    const int row0 = rowblk * 256, col0 = colblk * 256;

    const int tid = threadIdx.x;
    const int lane = tid & 63;
    const int wv = tid >> 6;          // 0..7
    const int wm = wv >> 2, wn = wv & 3;
    const int lr = lane & 15, kg = lane >> 4;

    // ---- staging source addresses (pre-swizzled global chunks) ----
    const int srow = tid >> 2;        // dest row (mod 128)
    const int sc = tid & 3;           // dest 16B-chunk position
    const int kch = ((sc ^ ((srow >> 1) & 3)) << 3);  // source k-chunk (elements)
    const __hip_bfloat16* As0 = A + (size_t)(row0 + srow) * K + kch;
    const __hip_bfloat16* As1 = A + (size_t)(row0 + 128 + srow) * K + kch;
    const __hip_bfloat16* Bs0 = Bw + (size_t)(col0 + srow) * K + kch;
    const __hip_bfloat16* Bs1 = Bw + (size_t)(col0 + 128 + srow) * K + kch;

    auto STAGE_A = [&](int b, int k0) {
        __hip_bfloat16* la = sm + b * 16384 + wv * 512;  // per-wave uniform base
        gload16(la,        As0 + k0);
        gload16(la + 4096, As1 + k0);
    };
    auto STAGE_B = [&](int b, int k0) {
        __hip_bfloat16* lb = sm + b * 16384 + 8192 + wv * 512;
        gload16(lb,        Bs0 + k0);
        gload16(lb + 4096, Bs1 + k0);
    };

    // ---- ds_read fragment offsets (swizzled chunk) ----
    const int f = (lr >> 1) & 3;
    const int koff = ((kg ^ f) << 3);
    const int aoff = (wm * 128 + lr) * 32 + koff;          // A: elements
    const int boff = 8192 + (wn * 64 + lr) * 32 + koff;    // B: elements

    f32x4 acc[8][4];
#pragma unroll
    for (int i = 0; i < 8; ++i)
#pragma unroll
        for (int j = 0; j < 4; ++j) acc[i][j] = (f32x4){0.f, 0.f, 0.f, 0.f};

    constexpr int nt = K / 32;
    STAGE_A(0, 0);  STAGE_B(0, 0);
    STAGE_A(1, 32); STAGE_B(1, 32);

    for (int t = 0; t < nt; ++t) {
        if (t + 1 < nt) {
            asm volatile("s_waitcnt vmcnt(4)" ::: "memory");  // tile t landed
        } else {
            asm volatile("s_waitcnt vmcnt(0)" ::: "memory");
        }
        __builtin_amdgcn_s_barrier();
        __builtin_amdgcn_sched_barrier(0);  // keep reads below the barrier

        const __hip_bfloat16* base = sm + (t % 3) * 16384;
        bf16x8 af[8], bfr[4];

        if (t + 2 < nt) {
            STAGE_A((t + 2) % 3, (t + 2) * 32);
            STAGE_B((t + 2) % 3, (t + 2) * 32);
        }
#pragma unroll
        for (int i = 0; i < 8; ++i)
            af[i] = *reinterpret_cast<const bf16x8*>(base + aoff + i * 512);
#pragma unroll
        for (int j = 0; j < 4; ++j)
            bfr[j] = *reinterpret_cast<const bf16x8*>(base + boff + j * 512);

#pragma unroll
        for (int i = 0; i < 8; ++i)
#pragma unroll
            for (int j = 0; j < 4; ++j)
                acc[i][j] = __builtin_amdgcn_mfma_f32_16x16x32_bf16(af[i], bfr[j], acc[i][j], 0, 0, 0);
        // no end-fence: next iteration's vmcnt+barrier orders everything
    }

    // ---- epilogue: BN + LeakyReLU (+ xq for MODE 1), write-combined -------
    const int bq = row0 >> 11;  // batch index (tile rows within one batch)
    float scl[4], tcn[4], xqv[4];
#pragma unroll
    for (int j = 0; j < 4; ++j) {
        const int c = col0 + wn * 64 + j * 16 + lr;
        scl[j] = Gg[c] * rsqrtf(Gv[c] + 1e-5f);
        tcn[j] = Gb[c] - Gm[c] * scl[j];
        xqv[j] = (MODE == 1) ? xq[bq * 2048 + c] : 0.f;
    }
#pragma unroll
    for (int i = 0; i < 8; ++i) {
#pragma unroll
        for (int rI = 0; rI < 4; ++rI) {
            const int r = row0 + wm * 128 + i * 16 + kg * 4 + rI;
            const size_t rowoff = (size_t)r * N + col0 + wn * 64 + lr;
#pragma unroll
            for (int j = 0; j < 4; ++j) {
                float val = acc[i][j][rI] * scl[j] + tcn[j];
                val = LRELU(val) + xqv[j];
                out[rowoff + j * 16] = __float2bfloat16(val);
            }
        }
    }
}

// ---------------- GEMM3 (M x 64, K=512) fused with layer-4 + bn4 ----------
__global__ __launch_bounds__(256)
void gemm3_l4(const __hip_bfloat16* __restrict__ A,    // s2b [M,512]
              const __hip_bfloat16* __restrict__ W3b,  // [64,512]
              const float* __restrict__ W4,            // [64]
              const float* __restrict__ g3, const float* __restrict__ b3,
              const float* __restrict__ m3, const float* __restrict__ v3,
              const float* __restrict__ g4, const float* __restrict__ b4,
              const float* __restrict__ m4, const float* __restrict__ v4,
              float* __restrict__ logits) {
    const int lane = threadIdx.x & 63;
    const int wv = threadIdx.x >> 6;
    const int row0 = blockIdx.x * 128 + wv * 32;
    const int lr = lane & 15, kg = lane >> 4;

    f32x4 acc[2][4];
#pragma unroll
    for (int i = 0; i < 2; ++i)
#pragma unroll
        for (int j = 0; j < 4; ++j) acc[i][j] = (f32x4){0.f, 0.f, 0.f, 0.f};

    for (int k = 0; k < 512; k += 32) {
        const int kk = k + kg * 8;
        bf16x8 a[2], b[4];
#pragma unroll
        for (int i = 0; i < 2; ++i)
            a[i] = *reinterpret_cast<const bf16x8*>(A + (size_t)(row0 + i * 16 + lr) * 512 + kk);
#pragma unroll
        for (int j = 0; j < 4; ++j)
            b[j] = *reinterpret_cast<const bf16x8*>(W3b + (size_t)(j * 16 + lr) * 512 + kk);
#pragma unroll
        for (int i = 0; i < 2; ++i)
#pragma unroll
            for (int j = 0; j < 4; ++j)
                acc[i][j] = __builtin_amdgcn_mfma_f32_16x16x32_bf16(a[i], b[j], acc[i][j], 0, 0, 0);
    }

    const float sc4 = g4[0] * rsqrtf(v4[0] + 1e-5f);
    const float tc4 = b4[0] - m4[0] * sc4;
#pragma unroll
    for (int i = 0; i < 2; ++i) {
        float t[4] = {0.f, 0.f, 0.f, 0.f};
#pragma unroll
        for (int j = 0; j < 4; ++j) {
            const int c = j * 16 + lr;
            const float sc = g3[c] * rsqrtf(v3[c] + 1e-5f);
            const float tc = b3[c] - m3[c] * sc;
            const float w4c = W4[c];
#pragma unroll
            for (int rI = 0; rI < 4; ++rI) {
                float v = acc[i][j][rI] * sc + tc;
                t[rI] += LRELU(v) * w4c;
            }
        }
#pragma unroll
        for (int m = 1; m < 16; m <<= 1)
#pragma unroll
            for (int rI = 0; rI < 4; ++rI) t[rI] += __shfl_xor(t[rI], m, 64);
        if (lr == 0) {
#pragma unroll
            for (int rI = 0; rI < 4; ++rI) {
                float lg = t[rI] * sc4 + tc4;
                logits[row0 + i * 16 + kg * 4 + rI] = LRELU(lg);
            }
        }
    }
}

// ---------------- softmax over N=2048 per batch ----------------------------
__global__ void softmax2048(const float* __restrict__ logits, float* __restrict__ scores) {
    __shared__ float sh[2048];
    __shared__ float red[256];
    const int b = blockIdx.x, tid = threadIdx.x;
    float lmax = -1e30f;
#pragma unroll
    for (int it = 0; it < 8; ++it) {
        const int n = tid + it * 256;
        float v = logits[b * 2048 + n];
        sh[n] = v;
        lmax = fmaxf(lmax, v);
    }
    red[tid] = lmax;
    __syncthreads();
    for (int s = 128; s > 0; s >>= 1) {
        if (tid < s) red[tid] = fmaxf(red[tid], red[tid + s]);
        __syncthreads();
    }
    const float gmax = red[0];
    __syncthreads();
    float lsum = 0.f;
#pragma unroll
    for (int it = 0; it < 8; ++it) {
        const int n = tid + it * 256;
        float e = expf(sh[n] - gmax);
        sh[n] = e;
        lsum += e;
    }
    red[tid] = lsum;
    __syncthreads();
    for (int s = 128; s > 0; s >>= 1) {
        if (tid < s) red[tid] += red[tid + s];
        __syncthreads();
    }
    const float inv = 1.f / red[0];
#pragma unroll
    for (int it = 0; it < 8; ++it) {
        const int n = tid + it * 256;
        scores[b * 2048 + n] = sh[n] * inv;
    }
}

// ---------------- pooling over features, then subtract xq ------------------
// out[b,e] = sum_n features[b,n,e]*scores[b,n] - xq[b,e]   (sum scores = 1)
__global__ void pool_partial(const __hip_bfloat16* __restrict__ feats,
                             const float* __restrict__ scores,
                             float* __restrict__ partial) {
    const int b = blockIdx.y, nc = blockIdx.x;  // 32 chunks of 64 rows
    const int e0 = threadIdx.x * 8;
    float acc[8] = {0, 0, 0, 0, 0, 0, 0, 0};
    const size_t base = ((size_t)b * 2048 + nc * 64) * 2048;
    for (int i = 0; i < 64; ++i) {
        const float sc = scores[b * 2048 + nc * 64 + i];
        bf16x8 v = *reinterpret_cast<const bf16x8*>(feats + base + (size_t)i * 2048 + e0);
#pragma unroll
        for (int j = 0; j < 8; ++j) acc[j] += sc * (float)v[j];
    }
    float* p = partial + ((size_t)(b * 32 + nc)) * 2048 + e0;
#pragma unroll
    for (int j = 0; j < 8; ++j) p[j] = acc[j];
}

__global__ void pool_reduce(const float* __restrict__ partial,
                            const float* __restrict__ xq,
                            float* __restrict__ out) {
    const int i = blockIdx.x * blockDim.x + threadIdx.x;  // 0..32767
    const int b = i >> 11, e = i & 2047;
    float s = 0.f;
#pragma unroll
    for (int nc = 0; nc < 32; ++nc) s += partial[((size_t)(b * 32 + nc)) * 2048 + e];
    out[i] = s - xq[i];
}

// ---------------------------------------------------------------------------
extern "C" void kernel_launch(void* const* d_in, const int* in_sizes, int n_in,
                              void* d_out, int out_size, void* d_ws, size_t ws_size,
                              hipStream_t stream) {
    const float* xq = (const float*)d_in[0];
    const float* xk = (const float*)d_in[1];
    const float* W1 = (const float*)d_in[2];
    const float* W2 = (const float*)d_in[3];
    const float* W3 = (const float*)d_in[4];
    const float* W4 = (const float*)d_in[5];
    const float* g1 = (const float*)d_in[6], *b1 = (const float*)d_in[7];
    const float* m1 = (const float*)d_in[8], *v1 = (const float*)d_in[9];
    const float* g2 = (const float*)d_in[10], *b2 = (const float*)d_in[11];
    const float* m2 = (const float*)d_in[12], *v2 = (const float*)d_in[13];
    const float* g3 = (const float*)d_in[14], *b3 = (const float*)d_in[15];
    const float* m3 = (const float*)d_in[16], *v3 = (const float*)d_in[17];
    const float* g4 = (const float*)d_in[18], *b4 = (const float*)d_in[19];
    const float* m4 = (const float*)d_in[20], *v4 = (const float*)d_in[21];

    const int M = 32768;  // B*N = 16*2048

    char* ws = (char*)d_ws;
    size_t off = 0;
    auto alloc = [&](size_t bytes) {
        void* p = ws + off;
        off += (bytes + 255) & ~(size_t)255;
        return p;
    };
    __hip_bfloat16* xkb   = (__hip_bfloat16*)alloc((size_t)M * 512 * 2);
    __hip_bfloat16* w1b   = (__hip_bfloat16*)alloc((size_t)2048 * 512 * 2);
    __hip_bfloat16* w2b   = (__hip_bfloat16*)alloc((size_t)512 * 2048 * 2);
    __hip_bfloat16* w3b   = (__hip_bfloat16*)alloc((size_t)64 * 512 * 2);
    __hip_bfloat16* featb = (__hip_bfloat16*)alloc((size_t)M * 2048 * 2);
    __hip_bfloat16* s2b   = (__hip_bfloat16*)alloc((size_t)M * 512 * 2);
    float* logits         = (float*)alloc((size_t)M * 4);
    float* scores         = (float*)alloc((size_t)16 * 2048 * 4);
    float* partial        = (float*)alloc((size_t)16 * 32 * 2048 * 4);

    // converts
    cvt_f32_bf16<<<4096, 256, 0, stream>>>(xk, xkb, M * 512 / 4);
    cvt_f32_bf16<<<1024, 256, 0, stream>>>(W1, w1b, 2048 * 512 / 4);
    cvt_f32_bf16<<<1024, 256, 0, stream>>>(W2, w2b, 512 * 2048 / 4);
    cvt_f32_bf16<<<32, 256, 0, stream>>>(W3, w3b, 64 * 512 / 4);

    // GEMM1: features = lrelu(bn1(xk @ W1^T)) + xq   [M,2048] bf16
    gemm256<2048, 512, 1><<<1024, 512, 0, stream>>>(
        xkb, w1b, xq, featb, g1, b1, m1, v1);

    // GEMM2: s2 = lrelu(bn2(features @ W2^T))        [M,512] bf16
    gemm256<512, 2048, 2><<<256, 512, 0, stream>>>(
        featb, w2b, nullptr, s2b, g2, b2, m2, v2);

    // GEMM3 + layer4: logits [M] f32
    gemm3_l4<<<256, 256, 0, stream>>>(s2b, w3b, W4,
                                      g3, b3, m3, v3, g4, b4, m4, v4, logits);

    // softmax over N per batch
    softmax2048<<<16, 256, 0, stream>>>(logits, scores);

    // pooling (+ subtract xq)
    pool_partial<<<dim3(32, 16), 256, 0, stream>>>(featb, scores, partial);
    pool_reduce<<<128, 256, 0, stream>>>(partial, xq, (float*)d_out);
}